// Round 12
// baseline (153.314 us; speedup 1.0000x reference)
//
#include <hip/hip_runtime.h>
#include <hip/hip_bf16.h>

#define NB 2
#define NS 2048
#define NH 16
#define ND 128
#define SROW (NH*ND)   // floats between consecutive s in [B,S,H,D] (= 2048)

#define QBLK 128       // q rows per block (4 waves x 32 q)
#define KBLK 64
#define NTHR 256
#define NT   (NS/KBLK) // 32 tiles

#define VSTR 72    // shorts; V^T LDS row stride (144 B, odd multiple of 16B)

typedef __attribute__((ext_vector_type(4))) float f32x4;
typedef __attribute__((ext_vector_type(8))) __bf16 bf16x8;
typedef __attribute__((ext_vector_type(4))) __bf16 bf16x4;
typedef __attribute__((ext_vector_type(8))) short s16x8;
typedef __attribute__((ext_vector_type(4))) short s16x4;

__device__ __forceinline__ short f2bf(float f) {
  union { float f; unsigned u; } v; v.f = f;
  unsigned r = v.u + 0x7fffu + ((v.u >> 16) & 1u);
  return (short)(r >> 16);
}

// ---------------- pre-pass: K -> bf16 [B,H,S,D], scale*log2e folded ----------------
__global__ __launch_bounds__(256)
void prep_k(const float* __restrict__ K, short* __restrict__ Kb) {
  const float sc = 0.08838834764831845f * 1.4426950408889634f;
  size_t i = (size_t)blockIdx.x * 256 + threadIdx.x;
  int g = (int)(i & 31);
  size_t row = i >> 5;
  int h = (int)(row & (NH - 1));
  size_t bs = row >> 4;
  int s = (int)(bs & (NS - 1));
  int b = (int)(bs >> 11);
  float4 x = *(const float4*)(K + row * ND + g * 4);
  bf16x4 w = { (__bf16)(x.x * sc), (__bf16)(x.y * sc), (__bf16)(x.z * sc), (__bf16)(x.w * sc) };
  *(bf16x4*)(Kb + ((size_t)(b * NH + h) * NS + s) * ND + g * 4) = w;
}

// ---------------- pre-pass: V -> bf16 transposed [B,H,D,S] ----------------
__global__ __launch_bounds__(256)
void prep_v(const float* __restrict__ V, short* __restrict__ VT) {
  __shared__ short tile[64 * 72];
  int gid = blockIdx.x;
  int st = gid & 31;
  int dt = (gid >> 5) & 1;
  int bh = gid >> 6;
  int b = bh >> 4, h = bh & 15;
  int s0 = st * 64, d0 = dt * 64;
  const float* src = V + ((size_t)b * NS * NH + h) * ND;
#pragma unroll
  for (int it = 0; it < 4; ++it) {
    int idx = threadIdx.x + it * 256;
    int r = idx >> 4;
    int c = (idx & 15) * 4;
    float4 x = *(const float4*)(src + (size_t)(s0 + r) * SROW + d0 + c);
    bf16x4 w = { (__bf16)x.x, (__bf16)x.y, (__bf16)x.z, (__bf16)x.w };
    *(bf16x4*)&tile[r * 72 + c] = w;
  }
  __syncthreads();
  short* dst = VT + (size_t)bh * ND * NS;
#pragma unroll
  for (int it = 0; it < 2; ++it) {
    int idx = threadIdx.x + it * 256;
    int dr = idx >> 3;
    int c8 = (idx & 7) * 8;
    s16x8 w;
#pragma unroll
    for (int j = 0; j < 8; ++j) w[j] = tile[(c8 + j) * 72 + dr];
    *(s16x8*)(dst + (size_t)(d0 + dr) * NS + s0 + c8) = w;
  }
}

// -- main attention: K streamed global->reg (dbuf groups, NO K LDS),
//    V via dbuf LDS, no-max softmax, deferred PV, single barrier/tile --
__global__ __launch_bounds__(NTHR, 2)
void attn_fwd12(const float* __restrict__ Q, const short* __restrict__ Kb,
                const short* __restrict__ VTb, float* __restrict__ O)
{
  __shared__ __align__(16) short vbuf[2][ND * VSTR];   // 2 x 18432 B = 36.9 KB total

  const int tid  = threadIdx.x;
  const int wave = tid >> 6;
  const int lane = tid & 63;
  const int g    = lane >> 4;
  const int lr   = lane & 15;

  // XCD-aware swizzle: blocks on one XCD cover 4 bh -> 2 MB K per XCD (L2-hot).
  const int L  = blockIdx.x;
  const int bh = (L & 7) + 8 * ((L >> 3) & 3);   // 0..31
  const int qb = L >> 5;                         // 0..15
  const int b  = bh >> 4;
  const int h  = bh & 15;

  const float* Qb = Q + ((size_t)b * NS * NH + h) * ND;
  float*       Ob = O + ((size_t)b * NS * NH + h) * ND;
  const short* Kbh = Kb  + (size_t)bh * NS * ND;
  const short* Vbh = VTb + (size_t)bh * ND * NS;

  const int wq0 = qb * QBLK + wave * 32;   // this wave's first q row (owns 32)

  // ---- Q fragments (B-operand layout), bf16 ----
  bf16x8 qf[2][4];
#pragma unroll
  for (int qt = 0; qt < 2; ++qt) {
    const float* qp = Qb + (size_t)(wq0 + qt * 16 + lr) * SROW;
#pragma unroll
    for (int kc = 0; kc < 4; ++kc) {
      const int d0 = kc * 32 + g * 8;
      float4 a = *(const float4*)(qp + d0);
      float4 c = *(const float4*)(qp + d0 + 4);
      bf16x8 f;
      f[0] = (__bf16)a.x; f[1] = (__bf16)a.y; f[2] = (__bf16)a.z; f[3] = (__bf16)a.w;
      f[4] = (__bf16)c.x; f[5] = (__bf16)c.y; f[6] = (__bf16)c.z; f[7] = (__bf16)c.w;
      qf[qt][kc] = f;
    }
  }

  f32x4 oacc[2][8];
#pragma unroll
  for (int qt = 0; qt < 2; ++qt)
#pragma unroll
    for (int dc = 0; dc < 8; ++dc) oacc[qt][dc] = (f32x4){0.f, 0.f, 0.f, 0.f};
  float lpart[2] = {0.f, 0.f};   // per-lane partial row sums (q = qt*16+lr)
  bf16x8 pf[2][2];               // P frags of PREVIOUS tile (deferred PV)

  // ---- V staging coords (kt-invariant) ----
  const int vc7 = tid & 7;
  const int ksb = vc7 >> 2, q4 = vc7 & 3;
  const int vcol0 = ksb * 32 + ((q4 * 2) & 3) * 8 + (q4 >> 1) * 4;
  const int vlo = (tid >> 3) * VSTR + vcol0;
  const short* vp = Vbh + (size_t)(tid >> 3) * NS + vc7 * 8;

  // ---- K fragment stream pointer: lane (g,lr) reads 8 contiguous bf16/frag ----
  const short* kq = Kbh + lr * ND + g * 8;

  s16x8 vreg[4];
  bf16x8 kfA[4], kfB[4];   // K-fragment group double buffer (prefetch depth 1 group)

#define KGROUP(DST, NB_)                                                       \
  {                                                                            \
    _Pragma("unroll")                                                          \
    for (int kc = 0; kc < 4; ++kc)                                             \
      DST[kc] = *(const bf16x8*)(kq + (NB_) * (16 * ND) + kc * 32);            \
  }

#define LOAD_V                                                                 \
  {                                                                            \
    _Pragma("unroll")                                                          \
    for (int it = 0; it < 4; ++it)                                             \
      vreg[it] = *(const s16x8*)(vp + (size_t)it * (32 * NS));                 \
    vp += KBLK;                                                                \
  }

#define WRITE_V(VL)                                                            \
  {                                                                            \
    _Pragma("unroll")                                                          \
    for (int it = 0; it < 4; ++it) {                                           \
      s16x8 v = vreg[it];                                                      \
      s16x4 vlo4 = __builtin_shufflevector(v, v, 0, 1, 2, 3);                  \
      s16x4 vhi4 = __builtin_shufflevector(v, v, 4, 5, 6, 7);                  \
      *(s16x4*)&(VL)[vlo + it * (32 * VSTR)]     = vlo4;                       \
      *(s16x4*)&(VL)[vlo + it * (32 * VSTR) + 8] = vhi4;                       \
    }                                                                          \
  }

#define QK_STEP(CUR, NBIDX)                                                    \
  {                                                                            \
    f32x4 a0 = {0.f, 0.f, 0.f, 0.f};                                           \
    f32x4 a1 = {0.f, 0.f, 0.f, 0.f};                                           \
    _Pragma("unroll")                                                          \
    for (int kc = 0; kc < 4; ++kc) {                                           \
      a0 = __builtin_amdgcn_mfma_f32_16x16x32_bf16(CUR[kc], qf[0][kc], a0, 0, 0, 0); \
      a1 = __builtin_amdgcn_mfma_f32_16x16x32_bf16(CUR[kc], qf[1][kc], a1, 0, 0, 0); \
    }                                                                          \
    sacc[0][NBIDX] = a0;                                                       \
    sacc[1][NBIDX] = a1;                                                       \
  }

// K groups stream with one-group prefetch: load group n+1 while MFMA on group n.
// The nb=3 step prefetches NEXT TILE's group 0 (kq advanced). At the final tile
// this reads past this bh's K into adjacent workspace (valid memory, unused data).
#define QK_SOFTMAX                                                             \
  {                                                                            \
    f32x4 sacc[2][4];                                                          \
    __builtin_amdgcn_s_setprio(1);                                             \
    KGROUP(kfB, 1); QK_STEP(kfA, 0);                                           \
    KGROUP(kfA, 2); QK_STEP(kfB, 1);                                           \
    KGROUP(kfB, 3); QK_STEP(kfA, 2);                                           \
    kq += KBLK * ND;                                                           \
    KGROUP(kfA, 0); QK_STEP(kfB, 3);                                           \
    __builtin_amdgcn_s_setprio(0);                                             \
    _Pragma("unroll")                                                          \
    for (int qt = 0; qt < 2; ++qt) {                                           \
      _Pragma("unroll")                                                        \
      for (int nb = 0; nb < 4; ++nb)                                           \
        _Pragma("unroll")                                                      \
        for (int i = 0; i < 4; ++i) {                                          \
          float p = exp2f(sacc[qt][nb][i]);                                    \
          sacc[qt][nb][i] = p;                                                 \
          lpart[qt] += p;                                                      \
        }                                                                      \
      bf16x8 t0, t1;                                                           \
      _Pragma("unroll")                                                        \
      for (int i = 0; i < 4; ++i) {                                            \
        t0[i]     = (__bf16)sacc[qt][0][i];                                    \
        t0[i + 4] = (__bf16)sacc[qt][1][i];                                    \
        t1[i]     = (__bf16)sacc[qt][2][i];                                    \
        t1[i + 4] = (__bf16)sacc[qt][3][i];                                    \
      }                                                                        \
      pf[qt][0] = t0;                                                          \
      pf[qt][1] = t1;                                                          \
    }                                                                          \
  }

#define PV_STEP(VL)                                                            \
  {                                                                            \
    __builtin_amdgcn_s_setprio(1);                                             \
    _Pragma("unroll")                                                          \
    for (int dc = 0; dc < 8; ++dc) {                                           \
      bf16x8 vf0 = *(const bf16x8*)&(VL)[(dc * 16 + lr) * VSTR + g * 8];       \
      bf16x8 vf1 = *(const bf16x8*)&(VL)[(dc * 16 + lr) * VSTR + 32 + g * 8];  \
      oacc[0][dc] = __builtin_amdgcn_mfma_f32_16x16x32_bf16(pf[0][0], vf0, oacc[0][dc], 0, 0, 0); \
      oacc[1][dc] = __builtin_amdgcn_mfma_f32_16x16x32_bf16(pf[1][0], vf0, oacc[1][dc], 0, 0, 0); \
      oacc[0][dc] = __builtin_amdgcn_mfma_f32_16x16x32_bf16(pf[0][1], vf1, oacc[0][dc], 0, 0, 0); \
      oacc[1][dc] = __builtin_amdgcn_mfma_f32_16x16x32_bf16(pf[1][1], vf1, oacc[1][dc], 0, 0, 0); \
    }                                                                          \
    __builtin_amdgcn_s_setprio(0);                                             \
  }

  // ---- prologue: tile 0 ----
  LOAD_V;                           // V(0) -> regs
  WRITE_V(vbuf[0]);                 // V(0) -> LDS
  KGROUP(kfA, 0);                   // K(0) group 0 -> regs
  LOAD_V;                           // V(1) -> regs (in flight across barrier)
  __syncthreads();
  QK_SOFTMAX;                       // tile 0: S, exp, pack -> pf; kfA = K(1) g0

  // ---- main loop: tiles 1..NT-1; single barrier per tile ----
#pragma unroll 2
  for (int kt = 1; kt < NT; ++kt) {
    short* vl  = vbuf[kt & 1];
    short* vlp = vbuf[(kt & 1) ^ 1];

    WRITE_V(vl);                    // staged V(kt) -> LDS
    if (kt + 1 < NT) LOAD_V;        // issue V(kt+1) global loads
    PV_STEP(vlp);                   // deferred PV(kt-1)
    __syncthreads();                // V(kt) visible; PV(kt-1) drained
    QK_SOFTMAX;                     // S(kt) from global-streamed K, exp, pack
  }

  // ---- epilogue: PV(NT-1) ----
  {
    short* vlp = vbuf[(NT - 1) & 1];
    PV_STEP(vlp);
  }

  // ---- final row-sum reduce, normalize, store ----
#pragma unroll
  for (int qt = 0; qt < 2; ++qt) {
    float l = lpart[qt];
    l += __shfl_xor(l, 16);
    l += __shfl_xor(l, 32);
    float inv = 1.0f / l;
#pragma unroll
    for (int i = 0; i < 4; ++i) {
      float invm = __shfl(inv, g * 4 + i);
      float* orow = Ob + (size_t)(wq0 + qt * 16 + g * 4 + i) * SROW;
#pragma unroll
      for (int dc = 0; dc < 8; ++dc)
        orow[dc * 16 + lr] = oacc[qt][dc][i] * invm;
    }
  }
#undef KGROUP
#undef LOAD_V
#undef WRITE_V
#undef QK_STEP
#undef QK_SOFTMAX
#undef PV_STEP
}

// ---------------- legacy fallback (fp32 staging, QBLK=64) ----------------
__global__ __launch_bounds__(256, 2)
void attn_fwd_legacy(const float* __restrict__ Q, const float* __restrict__ K,
                     const float* __restrict__ V, float* __restrict__ O)
{
  __shared__ __align__(16) short k_lds[64 * 136];
  __shared__ __align__(16) short vt_lds[ND * 72];
  __shared__ __align__(16) short p_lds[4 * 16 * 72];

  const int tid = threadIdx.x;
  const int wave = tid >> 6;
  const int lane = tid & 63;
  const int g = lane >> 4;
  const int lr = lane & 15;

  const int nqb = NS / 64;
  const int qb = blockIdx.x % nqb;
  const int bh = blockIdx.x / nqb;
  const int b = bh / NH;
  const int h = bh % NH;

  const float scale = 0.08838834764831845f * 1.4426950408889634f;
  const size_t base = ((size_t)b * NS * NH + h) * ND;
  const float* Qb = Q + base;
  const float* Kbp = K + base;
  const float* Vb = V + base;
  float* Ob = O + base;
  const int q0 = qb * 64 + wave * 16;

  bf16x8 qf[4];
  {
    const float* qp = Qb + (size_t)(q0 + lr) * SROW;
#pragma unroll
    for (int kc = 0; kc < 4; ++kc) {
      const int d0 = kc * 32 + g * 8;
      float4 a = *(const float4*)(qp + d0);
      float4 c = *(const float4*)(qp + d0 + 4);
      s16x8 f;
      f[0] = f2bf(a.x * scale); f[1] = f2bf(a.y * scale);
      f[2] = f2bf(a.z * scale); f[3] = f2bf(a.w * scale);
      f[4] = f2bf(c.x * scale); f[5] = f2bf(c.y * scale);
      f[6] = f2bf(c.z * scale); f[7] = f2bf(c.w * scale);
      qf[kc] = __builtin_bit_cast(bf16x8, f);
    }
  }

  f32x4 oacc[8];
#pragma unroll
  for (int dc = 0; dc < 8; ++dc) oacc[dc] = (f32x4){0.f, 0.f, 0.f, 0.f};
  float mrun[4] = {-1e30f, -1e30f, -1e30f, -1e30f};
  float lrun[4] = {0.f, 0.f, 0.f, 0.f};

  for (int kt = 0; kt < NS / 64; ++kt) {
    const int kv0 = kt * 64;
    __syncthreads();
#pragma unroll
    for (int it = 0; it < 8; ++it) {
      int idx = tid + it * 256;
      int r = idx >> 5;
      int c = (idx & 31) << 2;
      float4 x = *(const float4*)(Kbp + (size_t)(kv0 + r) * SROW + c);
      s16x4 w = { f2bf(x.x), f2bf(x.y), f2bf(x.z), f2bf(x.w) };
      *(s16x4*)&k_lds[r * 136 + c] = w;
    }
#pragma unroll
    for (int it = 0; it < 2; ++it) {
      int sub = tid + it * 256;
      int skv = (sub >> 5) << 2;
      int sd = (sub & 31) << 2;
      const float* vp = Vb + (size_t)(kv0 + skv) * SROW + sd;
      float4 r0 = *(const float4*)(vp);
      float4 r1 = *(const float4*)(vp + SROW);
      float4 r2 = *(const float4*)(vp + 2 * SROW);
      float4 r3 = *(const float4*)(vp + 3 * SROW);
      s16x4 w0 = { f2bf(r0.x), f2bf(r1.x), f2bf(r2.x), f2bf(r3.x) };
      s16x4 w1 = { f2bf(r0.y), f2bf(r1.y), f2bf(r2.y), f2bf(r3.y) };
      s16x4 w2 = { f2bf(r0.z), f2bf(r1.z), f2bf(r2.z), f2bf(r3.z) };
      s16x4 w3 = { f2bf(r0.w), f2bf(r1.w), f2bf(r2.w), f2bf(r3.w) };
      *(s16x4*)&vt_lds[(sd + 0) * 72 + skv] = w0;
      *(s16x4*)&vt_lds[(sd + 1) * 72 + skv] = w1;
      *(s16x4*)&vt_lds[(sd + 2) * 72 + skv] = w2;
      *(s16x4*)&vt_lds[(sd + 3) * 72 + skv] = w3;
    }
    __syncthreads();

    f32x4 sacc[4];
#pragma unroll
    for (int nb = 0; nb < 4; ++nb) {
      f32x4 acc = {0.f, 0.f, 0.f, 0.f};
#pragma unroll
      for (int kc = 0; kc < 4; ++kc) {
        bf16x8 kfr = *(const bf16x8*)&k_lds[(nb * 16 + lr) * 136 + kc * 32 + g * 8];
        acc = __builtin_amdgcn_mfma_f32_16x16x32_bf16(qf[kc], kfr, acc, 0, 0, 0);
      }
      sacc[nb] = acc;
    }

    float alpha[4];
#pragma unroll
    for (int i = 0; i < 4; ++i) {
      float m = fmaxf(fmaxf(sacc[0][i], sacc[1][i]), fmaxf(sacc[2][i], sacc[3][i]));
#pragma unroll
      for (int off = 1; off < 16; off <<= 1) m = fmaxf(m, __shfl_xor(m, off));
      float mnew = fmaxf(mrun[i], m);
      alpha[i] = exp2f(mrun[i] - mnew);
      mrun[i] = mnew;
    }
    float rsum[4] = {0.f, 0.f, 0.f, 0.f};
#pragma unroll
    for (int nb = 0; nb < 4; ++nb)
#pragma unroll
      for (int i = 0; i < 4; ++i) {
        float p = exp2f(sacc[nb][i] - mrun[i]);
        sacc[nb][i] = p;
        rsum[i] += p;
      }
#pragma unroll
    for (int i = 0; i < 4; ++i) {
#pragma unroll
      for (int off = 1; off < 16; off <<= 1) rsum[i] += __shfl_xor(rsum[i], off);
      lrun[i] = lrun[i] * alpha[i] + rsum[i];
    }
#pragma unroll
    for (int dc = 0; dc < 8; ++dc)
#pragma unroll
      for (int i = 0; i < 4; ++i) oacc[dc][i] *= alpha[i];

    short* pw = &p_lds[wave * 16 * 72];
#pragma unroll
    for (int nb = 0; nb < 4; ++nb)
#pragma unroll
      for (int i = 0; i < 4; ++i)
        pw[(g * 4 + i) * 72 + nb * 16 + lr] = f2bf(sacc[nb][i]);

    bf16x8 pf0 = *(const bf16x8*)&pw[lr * 72 + g * 8];
    bf16x8 pf1 = *(const bf16x8*)&pw[lr * 72 + 32 + g * 8];

#pragma unroll
    for (int dc = 0; dc < 8; ++dc) {
      bf16x8 vf0 = *(const bf16x8*)&vt_lds[(dc * 16 + lr) * 72 + g * 8];
      oacc[dc] = __builtin_amdgcn_mfma_f32_16x16x32_bf16(pf0, vf0, oacc[dc], 0, 0, 0);
      bf16x8 vf1 = *(const bf16x8*)&vt_lds[(dc * 16 + lr) * 72 + 32 + g * 8];
      oacc[dc] = __builtin_amdgcn_mfma_f32_16x16x32_bf16(pf1, vf1, oacc[dc], 0, 0, 0);
    }
  }

  float* op = Ob + (size_t)q0 * SROW;
#pragma unroll
  for (int i = 0; i < 4; ++i) {
    float inv = 1.0f / lrun[i];
    int m = g * 4 + i;
#pragma unroll
    for (int dc = 0; dc < 8; ++dc)
      op[(size_t)m * SROW + dc * 16 + lr] = oacc[dc][i] * inv;
  }
}

extern "C" void kernel_launch(void* const* d_in, const int* in_sizes, int n_in,
                              void* d_out, int out_size, void* d_ws, size_t ws_size,
                              hipStream_t stream) {
  const float* Q = (const float*)d_in[0];
  const float* K = (const float*)d_in[1];
  const float* V = (const float*)d_in[2];
  float* O = (float*)d_out;

  const size_t elems = (size_t)NB * NS * NH * ND;      // 8388608
  const size_t need = 2 * elems * sizeof(short) + 65536; // Kb + VT + OOB-prefetch pad

  if (ws_size >= need) {
    short* Kb = (short*)d_ws;
    short* VT = Kb + elems;
    hipLaunchKernelGGL(prep_k, dim3((unsigned)(elems / 4 / 256)), dim3(256), 0, stream, K, Kb);
    hipLaunchKernelGGL(prep_v, dim3(NB * NH * (NS / 64) * (ND / 64)), dim3(256), 0, stream, V, VT);
    hipLaunchKernelGGL(attn_fwd12, dim3(NB * NH * (NS / QBLK)), dim3(NTHR), 0, stream,
                       Q, Kb, VT, O);
  } else {
    hipLaunchKernelGGL(attn_fwd_legacy, dim3(NB * NH * (NS / 64)), dim3(256), 0, stream, Q, K, V, O);
  }
}

// Round 13
// 101.244 us; speedup vs baseline: 1.5143x; 1.5143x over previous
//
#include <hip/hip_runtime.h>
#include <hip/hip_bf16.h>

#define NB 2
#define NS 2048
#define NH 16
#define ND 128
#define SROW (NH*ND)   // floats between consecutive s in [B,S,H,D] (= 2048)

#define QBLK 128       // q rows per block (4 waves x 32 q)
#define KBLK 64
#define NTHR 256
#define NT   (NS/KBLK) // 32 tiles

// tile images: K = 64 kv x 128 d bf16 (256 B/row), V^T = 128 d x 64 kv bf16
// (128 B/row, kv-permuted), both XOR-swizzled: byte ^= ((row&7)<<4). 16384 B each.

typedef __attribute__((ext_vector_type(4))) float f32x4;
typedef __attribute__((ext_vector_type(8))) __bf16 bf16x8;
typedef __attribute__((ext_vector_type(4))) __bf16 bf16x4;
typedef __attribute__((ext_vector_type(8))) short s16x8;
typedef __attribute__((ext_vector_type(4))) short s16x4;

#define AS1(p) ((const __attribute__((address_space(1))) void*)(p))
#define AS3(p) ((__attribute__((address_space(3))) void*)(p))

__device__ __forceinline__ short f2bf(float f) {
  union { float f; unsigned u; } v; v.f = f;
  unsigned r = v.u + 0x7fffu + ((v.u >> 16) & 1u);
  return (short)(r >> 16);
}

// ---- pre-pass: K -> swizzled bf16 tile images [bh][kt][16384B], scale folded ----
__global__ __launch_bounds__(256)
void prep_k2(const float* __restrict__ K, char* __restrict__ Kp) {
  const float sc = 0.08838834764831845f * 1.4426950408889634f;
  size_t i = (size_t)blockIdx.x * 256 + threadIdx.x;   // one float4 per thread
  int g = (int)(i & 31);
  size_t row = i >> 5;                 // (b*S+s)*H + h
  int h = (int)(row & (NH - 1));
  size_t bs = row >> 4;
  int s = (int)(bs & (NS - 1));
  int b = (int)(bs >> 11);
  float4 x = *(const float4*)(K + row * ND + g * 4);
  bf16x4 w = { (__bf16)(x.x * sc), (__bf16)(x.y * sc), (__bf16)(x.z * sc), (__bf16)(x.w * sc) };
  int bh = b * NH + h;
  int kt = s >> 6, r = s & 63;
  int x8 = r * 256 + g * 8;                 // logical byte offset in tile image
  int swz = x8 ^ ((r & 7) << 4);            // bake read-side XOR swizzle
  *(bf16x4*)(Kp + (((size_t)(bh * 32 + kt)) << 14) + swz) = w;
}

// ---- pre-pass: V -> swizzled, kv-permuted V^T tile images [bh][kt][16384B] ----
__global__ __launch_bounds__(256)
void prep_v2(const float* __restrict__ V, char* __restrict__ Vp) {
  __shared__ short tile[64 * 136];         // [s-local][d], padded
  int gid = blockIdx.x;                    // 0..1023
  int kt = gid & 31;
  int bh = gid >> 5;                       // 0..31
  int b = bh >> 4, h = bh & 15;
  int s0 = kt * 64;
  const float* src = V + ((size_t)b * NS * NH + h) * ND;
#pragma unroll
  for (int it = 0; it < 8; ++it) {
    int idx = threadIdx.x + it * 256;      // 0..2047 float4s
    int r = idx >> 5;                      // s-local 0..63
    int c = (idx & 31) * 4;                // d
    float4 x = *(const float4*)(src + (size_t)(s0 + r) * SROW + c);
    bf16x4 w = { (__bf16)x.x, (__bf16)x.y, (__bf16)x.z, (__bf16)x.w };
    *(bf16x4*)&tile[r * 136 + c] = w;
  }
  __syncthreads();
  char* dst = Vp + (((size_t)(bh * 32 + kt)) << 14);
#pragma unroll
  for (int it = 0; it < 8; ++it) {
    int id = threadIdx.x + it * 256;       // 0..2047 8B chunks
    int d = id >> 4;                       // 0..127
    int c = (id >> 1) & 7;                 // kv chunk
    int half = id & 1;
    int kvb = c * 8 + half * 4;
    s16x4 w = { tile[(kvb + 0) * 136 + d], tile[(kvb + 1) * 136 + d],
                tile[(kvb + 2) * 136 + d], tile[(kvb + 3) * 136 + d] };
    // permuted col base (bytes): matches PV A-frag k-slot ordering
    int vb0 = (c >> 2) * 64 + (((c & 3) * 2) & 3) * 16 + ((c & 3) >> 1) * 8;
    int x = d * 128 + vb0 + half * 16;
    int swz = x ^ ((d & 7) << 4);
    *(s16x4*)(dst + swz) = w;
  }
}

// -- main attention: global_load_lds staging of prebaked images, 1 barrier/tile --
__global__ __launch_bounds__(NTHR, 2)
void attn_fwd13(const float* __restrict__ Q, const char* __restrict__ Kp,
                const char* __restrict__ Vp, float* __restrict__ O)
{
  __shared__ __align__(16) char klds[2 * 16384];
  __shared__ __align__(16) char vlds[2 * 16384];

  const int tid  = threadIdx.x;
  const int wave = tid >> 6;
  const int lane = tid & 63;
  const int g    = lane >> 4;
  const int lr   = lane & 15;

  // XCD-aware swizzle: blocks on one XCD cover 4 bh -> KV L2-local.
  const int L  = blockIdx.x;
  const int bh = (L & 7) + 8 * ((L >> 3) & 3);   // 0..31
  const int qb = L >> 5;                         // 0..15
  const int b  = bh >> 4;
  const int h  = bh & 15;

  const float* Qb = Q + ((size_t)b * NS * NH + h) * ND;
  float*       Ob = O + ((size_t)b * NS * NH + h) * ND;
  const char*  kimg = Kp + ((size_t)bh << 19);   // 32 tiles x 16384 B
  const char*  vimg = Vp + ((size_t)bh << 19);

  const int wq0 = qb * QBLK + wave * 32;   // this wave's first q row (owns 32)

  // ---- Q fragments (B-operand layout), bf16 ----
  bf16x8 qf[2][4];
#pragma unroll
  for (int qt = 0; qt < 2; ++qt) {
    const float* qp = Qb + (size_t)(wq0 + qt * 16 + lr) * SROW;
#pragma unroll
    for (int kc = 0; kc < 4; ++kc) {
      const int d0 = kc * 32 + g * 8;
      float4 a = *(const float4*)(qp + d0);
      float4 c = *(const float4*)(qp + d0 + 4);
      bf16x8 f;
      f[0] = (__bf16)a.x; f[1] = (__bf16)a.y; f[2] = (__bf16)a.z; f[3] = (__bf16)a.w;
      f[4] = (__bf16)c.x; f[5] = (__bf16)c.y; f[6] = (__bf16)c.z; f[7] = (__bf16)c.w;
      qf[qt][kc] = f;
    }
  }

  f32x4 oacc[2][8];
#pragma unroll
  for (int qt = 0; qt < 2; ++qt)
#pragma unroll
    for (int dc = 0; dc < 8; ++dc) oacc[qt][dc] = (f32x4){0.f, 0.f, 0.f, 0.f};
  float lpart[2] = {0.f, 0.f};   // per-lane partial row sums (q = qt*16+lr)

  // ---- swizzled read-address precompute (kt-invariant) ----
  const int kmask = (lr & 7) << 4;
  int kca[4];
#pragma unroll
  for (int kc = 0; kc < 4; ++kc)
    kca[kc] = (lr * 256 + kc * 64 + g * 16) ^ kmask;   // + nb*4096
  const int vca0 = (lr * 128 + g * 16) ^ kmask;        // + dc*2048
  const int vca1 = (lr * 128 + 64 + g * 16) ^ kmask;

  // ---- staging coords: per wave 4 KB of K + 4 KB of V per tile ----
  const int stago = wave * 4096 + lane * 16;   // per-lane global offset
  const int stagl = wave * 4096;               // wave-uniform LDS offset

#define STAGE(PAR, KT)                                                         \
  {                                                                            \
    const char* kg = kimg + ((size_t)(KT) << 14) + stago;                      \
    const char* vg = vimg + ((size_t)(KT) << 14) + stago;                      \
    _Pragma("unroll")                                                          \
    for (int ii = 0; ii < 4; ++ii) {                                           \
      __builtin_amdgcn_global_load_lds(AS1(kg + ii * 1024),                    \
          AS3(klds + (PAR) * 16384 + stagl + ii * 1024), 16, 0, 0);            \
      __builtin_amdgcn_global_load_lds(AS1(vg + ii * 1024),                    \
          AS3(vlds + (PAR) * 16384 + stagl + ii * 1024), 16, 0, 0);            \
    }                                                                          \
  }

  // ---- prologue: stage tile 0; barrier drains vmcnt -> resident ----
  STAGE(0, 0);
  __syncthreads();

#pragma unroll 2
  for (int kt = 0; kt < NT; ++kt) {
    const int po = (kt & 1) * 16384;

    // issue next tile's direct-to-LDS loads (other parity; full phase to land)
    if (kt + 1 < NT) STAGE((kt + 1) & 1, kt + 1);

    // ---- S^T = K Q^T (swizzled K reads) ----
    f32x4 sacc[2][4];
    __builtin_amdgcn_s_setprio(1);
#pragma unroll
    for (int nb = 0; nb < 4; ++nb) {
      f32x4 a0 = {0.f, 0.f, 0.f, 0.f};
      f32x4 a1 = {0.f, 0.f, 0.f, 0.f};
#pragma unroll
      for (int kc = 0; kc < 4; ++kc) {
        bf16x8 kf = *(const bf16x8*)(klds + po + nb * 4096 + kca[kc]);
        a0 = __builtin_amdgcn_mfma_f32_16x16x32_bf16(kf, qf[0][kc], a0, 0, 0, 0);
        a1 = __builtin_amdgcn_mfma_f32_16x16x32_bf16(kf, qf[1][kc], a1, 0, 0, 0);
      }
      sacc[0][nb] = a0;
      sacc[1][nb] = a1;
    }
    __builtin_amdgcn_s_setprio(0);

    // ---- no-max softmax + pack P into PV A-frags ----
    bf16x8 pf[2][2];
#pragma unroll
    for (int qt = 0; qt < 2; ++qt) {
#pragma unroll
      for (int nb = 0; nb < 4; ++nb)
#pragma unroll
        for (int i = 0; i < 4; ++i) {
          float p = exp2f(sacc[qt][nb][i]);
          sacc[qt][nb][i] = p;
          lpart[qt] += p;
        }
      bf16x8 t0, t1;
#pragma unroll
      for (int i = 0; i < 4; ++i) {
        t0[i]     = (__bf16)sacc[qt][0][i];
        t0[i + 4] = (__bf16)sacc[qt][1][i];
        t1[i]     = (__bf16)sacc[qt][2][i];
        t1[i + 4] = (__bf16)sacc[qt][3][i];
      }
      pf[qt][0] = t0;
      pf[qt][1] = t1;
    }

    // ---- O += P V (swizzled V reads; V-frag shared across q-subtiles) ----
    __builtin_amdgcn_s_setprio(1);
#pragma unroll
    for (int dc = 0; dc < 8; ++dc) {
      bf16x8 vf0 = *(const bf16x8*)(vlds + po + dc * 2048 + vca0);
      bf16x8 vf1 = *(const bf16x8*)(vlds + po + dc * 2048 + vca1);
      oacc[0][dc] = __builtin_amdgcn_mfma_f32_16x16x32_bf16(pf[0][0], vf0, oacc[0][dc], 0, 0, 0);
      oacc[1][dc] = __builtin_amdgcn_mfma_f32_16x16x32_bf16(pf[1][0], vf0, oacc[1][dc], 0, 0, 0);
      oacc[0][dc] = __builtin_amdgcn_mfma_f32_16x16x32_bf16(pf[0][1], vf1, oacc[0][dc], 0, 0, 0);
      oacc[1][dc] = __builtin_amdgcn_mfma_f32_16x16x32_bf16(pf[1][1], vf1, oacc[1][dc], 0, 0, 0);
    }
    __builtin_amdgcn_s_setprio(0);

    __syncthreads();   // drains next tile's gload_lds (vmcnt 0) + all LDS reads
  }

  // ---- final row-sum reduce, normalize, store ----
#pragma unroll
  for (int qt = 0; qt < 2; ++qt) {
    float l = lpart[qt];
    l += __shfl_xor(l, 16);
    l += __shfl_xor(l, 32);
    float inv = 1.0f / l;
#pragma unroll
    for (int i = 0; i < 4; ++i) {
      float invm = __shfl(inv, g * 4 + i);
      float* orow = Ob + (size_t)(wq0 + qt * 16 + g * 4 + i) * SROW;
#pragma unroll
      for (int dc = 0; dc < 8; ++dc)
        orow[dc * 16 + lr] = oacc[qt][dc][i] * invm;
    }
  }
#undef STAGE
}

// ---------------- legacy fallback (fp32 staging, QBLK=64) ----------------
__global__ __launch_bounds__(256, 2)
void attn_fwd_legacy(const float* __restrict__ Q, const float* __restrict__ K,
                     const float* __restrict__ V, float* __restrict__ O)
{
  __shared__ __align__(16) short k_lds[64 * 136];
  __shared__ __align__(16) short vt_lds[ND * 72];
  __shared__ __align__(16) short p_lds[4 * 16 * 72];

  const int tid = threadIdx.x;
  const int wave = tid >> 6;
  const int lane = tid & 63;
  const int g = lane >> 4;
  const int lr = lane & 15;

  const int nqb = NS / 64;
  const int qb = blockIdx.x % nqb;
  const int bh = blockIdx.x / nqb;
  const int b = bh / NH;
  const int h = bh % NH;

  const float scale = 0.08838834764831845f * 1.4426950408889634f;
  const size_t base = ((size_t)b * NS * NH + h) * ND;
  const float* Qb = Q + base;
  const float* Kbp = K + base;
  const float* Vb = V + base;
  float* Ob = O + base;
  const int q0 = qb * 64 + wave * 16;

  bf16x8 qf[4];
  {
    const float* qp = Qb + (size_t)(q0 + lr) * SROW;
#pragma unroll
    for (int kc = 0; kc < 4; ++kc) {
      const int d0 = kc * 32 + g * 8;
      float4 a = *(const float4*)(qp + d0);
      float4 c = *(const float4*)(qp + d0 + 4);
      s16x8 f;
      f[0] = f2bf(a.x * scale); f[1] = f2bf(a.y * scale);
      f[2] = f2bf(a.z * scale); f[3] = f2bf(a.w * scale);
      f[4] = f2bf(c.x * scale); f[5] = f2bf(c.y * scale);
      f[6] = f2bf(c.z * scale); f[7] = f2bf(c.w * scale);
      qf[kc] = __builtin_bit_cast(bf16x8, f);
    }
  }

  f32x4 oacc[8];
#pragma unroll
  for (int dc = 0; dc < 8; ++dc) oacc[dc] = (f32x4){0.f, 0.f, 0.f, 0.f};
  float mrun[4] = {-1e30f, -1e30f, -1e30f, -1e30f};
  float lrun[4] = {0.f, 0.f, 0.f, 0.f};

  for (int kt = 0; kt < NS / 64; ++kt) {
    const int kv0 = kt * 64;
    __syncthreads();
#pragma unroll
    for (int it = 0; it < 8; ++it) {
      int idx = tid + it * 256;
      int r = idx >> 5;
      int c = (idx & 31) << 2;
      float4 x = *(const float4*)(Kbp + (size_t)(kv0 + r) * SROW + c);
      s16x4 w = { f2bf(x.x), f2bf(x.y), f2bf(x.z), f2bf(x.w) };
      *(s16x4*)&k_lds[r * 136 + c] = w;
    }
#pragma unroll
    for (int it = 0; it < 2; ++it) {
      int sub = tid + it * 256;
      int skv = (sub >> 5) << 2;
      int sd = (sub & 31) << 2;
      const float* vp = Vb + (size_t)(kv0 + skv) * SROW + sd;
      float4 r0 = *(const float4*)(vp);
      float4 r1 = *(const float4*)(vp + SROW);
      float4 r2 = *(const float4*)(vp + 2 * SROW);
      float4 r3 = *(const float4*)(vp + 3 * SROW);
      s16x4 w0 = { f2bf(r0.x), f2bf(r1.x), f2bf(r2.x), f2bf(r3.x) };
      s16x4 w1 = { f2bf(r0.y), f2bf(r1.y), f2bf(r2.y), f2bf(r3.y) };
      s16x4 w2 = { f2bf(r0.z), f2bf(r1.z), f2bf(r2.z), f2bf(r3.z) };
      s16x4 w3 = { f2bf(r0.w), f2bf(r1.w), f2bf(r2.w), f2bf(r3.w) };
      *(s16x4*)&vt_lds[(sd + 0) * 72 + skv] = w0;
      *(s16x4*)&vt_lds[(sd + 1) * 72 + skv] = w1;
      *(s16x4*)&vt_lds[(sd + 2) * 72 + skv] = w2;
      *(s16x4*)&vt_lds[(sd + 3) * 72 + skv] = w3;
    }
    __syncthreads();

    f32x4 sacc[4];
#pragma unroll
    for (int nb = 0; nb < 4; ++nb) {
      f32x4 acc = {0.f, 0.f, 0.f, 0.f};
#pragma unroll
      for (int kc = 0; kc < 4; ++kc) {
        bf16x8 kfr = *(const bf16x8*)&k_lds[(nb * 16 + lr) * 136 + kc * 32 + g * 8];
        acc = __builtin_amdgcn_mfma_f32_16x16x32_bf16(qf[kc], kfr, acc, 0, 0, 0);
      }
      sacc[nb] = acc;
    }

    float alpha[4];
#pragma unroll
    for (int i = 0; i < 4; ++i) {
      float m = fmaxf(fmaxf(sacc[0][i], sacc[1][i]), fmaxf(sacc[2][i], sacc[3][i]));
#pragma unroll
      for (int off = 1; off < 16; off <<= 1) m = fmaxf(m, __shfl_xor(m, off));
      float mnew = fmaxf(mrun[i], m);
      alpha[i] = exp2f(mrun[i] - mnew);
      mrun[i] = mnew;
    }
    float rsum[4] = {0.f, 0.f, 0.f, 0.f};
#pragma unroll
    for (int nb = 0; nb < 4; ++nb)
#pragma unroll
      for (int i = 0; i < 4; ++i) {
        float p = exp2f(sacc[nb][i] - mrun[i]);
        sacc[nb][i] = p;
        rsum[i] += p;
      }
#pragma unroll
    for (int i = 0; i < 4; ++i) {
#pragma unroll
      for (int off = 1; off < 16; off <<= 1) rsum[i] += __shfl_xor(rsum[i], off);
      lrun[i] = lrun[i] * alpha[i] + rsum[i];
    }
#pragma unroll
    for (int dc = 0; dc < 8; ++dc)
#pragma unroll
      for (int i = 0; i < 4; ++i) oacc[dc][i] *= alpha[i];

    short* pw = &p_lds[wave * 16 * 72];
#pragma unroll
    for (int nb = 0; nb < 4; ++nb)
#pragma unroll
      for (int i = 0; i < 4; ++i)
        pw[(g * 4 + i) * 72 + nb * 16 + lr] = f2bf(sacc[nb][i]);

    bf16x8 pf0 = *(const bf16x8*)&pw[lr * 72 + g * 8];
    bf16x8 pf1 = *(const bf16x8*)&pw[lr * 72 + 32 + g * 8];

#pragma unroll
    for (int dc = 0; dc < 8; ++dc) {
      bf16x8 vf0 = *(const bf16x8*)&vt_lds[(dc * 16 + lr) * 72 + g * 8];
      oacc[dc] = __builtin_amdgcn_mfma_f32_16x16x32_bf16(pf0, vf0, oacc[dc], 0, 0, 0);
      bf16x8 vf1 = *(const bf16x8*)&vt_lds[(dc * 16 + lr) * 72 + 32 + g * 8];
      oacc[dc] = __builtin_amdgcn_mfma_f32_16x16x32_bf16(pf1, vf1, oacc[dc], 0, 0, 0);
    }
  }

  float* op = Ob + (size_t)q0 * SROW;
#pragma unroll
  for (int i = 0; i < 4; ++i) {
    float inv = 1.0f / lrun[i];
    int m = g * 4 + i;
#pragma unroll
    for (int dc = 0; dc < 8; ++dc)
      op[(size_t)m * SROW + dc * 16 + lr] = oacc[dc][i] * inv;
  }
}

extern "C" void kernel_launch(void* const* d_in, const int* in_sizes, int n_in,
                              void* d_out, int out_size, void* d_ws, size_t ws_size,
                              hipStream_t stream) {
  const float* Q = (const float*)d_in[0];
  const float* K = (const float*)d_in[1];
  const float* V = (const float*)d_in[2];
  float* O = (float*)d_out;

  const size_t elems = (size_t)NB * NS * NH * ND;      // 8388608
  const size_t need = 2 * elems * sizeof(short);       // Kp + Vp images, 33.5 MB

  if (ws_size >= need) {
    char* Kp = (char*)d_ws;
    char* Vp = Kp + elems * sizeof(short);
    hipLaunchKernelGGL(prep_k2, dim3((unsigned)(elems / 4 / 256)), dim3(256), 0, stream, K, Kp);
    hipLaunchKernelGGL(prep_v2, dim3(32 * 32), dim3(256), 0, stream, V, Vp);
    hipLaunchKernelGGL(attn_fwd13, dim3(NB * NH * (NS / QBLK)), dim3(NTHR), 0, stream,
                       Q, Kp, Vp, O);
  } else {
    hipLaunchKernelGGL(attn_fwd_legacy, dim3(NB * NH * (NS / 64)), dim3(256), 0, stream, Q, K, V, O);
  }
}